// Round 6
// baseline (280.501 us; speedup 1.0000x reference)
//
#include <hip/hip_runtime.h>
#include <stdint.h>

#define DD 2048
#define SS 2048
#define NB 2
#define NH 16
#define HDIM 128
#define MM (NB*SS)   // 4096 rows

typedef __attribute__((ext_vector_type(8))) short bf16x8;
typedef __attribute__((ext_vector_type(4))) float f32x4;
typedef __attribute__((ext_vector_type(4))) ushort u16x4;

__device__ __forceinline__ float fast_exp2(float x) {
  return __builtin_amdgcn_exp2f(x);   // v_exp_f32 (2^x natively)
}

__device__ __forceinline__ ushort f2bf(float f) {
  union { float f; uint32_t u; } v; v.f = f;
  uint32_t u = v.u;
  return (ushort)((u + 0x7fffu + ((u >> 16) & 1u)) >> 16);
}

__device__ __forceinline__ void gld_lds16(const ushort* g, ushort* l) {
  __builtin_amdgcn_global_load_lds(
      (const __attribute__((address_space(1))) void*)g,
      (__attribute__((address_space(3))) void*)l, 16, 0, 0);
}

// ---------------- fp32 -> bf16 conversion of x and the 4 weights -------------
__global__ __launch_bounds__(256) void cvt_all(
    const float* __restrict__ x, const float* __restrict__ wq,
    const float* __restrict__ wk, const float* __restrict__ wv,
    const float* __restrict__ wo, ushort* __restrict__ dst)
{
  int i8 = blockIdx.x * 256 + threadIdx.x;   // one 8-float chunk per thread
  const int X8 = MM * DD / 8;                // 1,048,576
  const int W8 = DD * DD / 8;                // 524,288
  const float* src; int off;
  if (i8 < X8)            { src = x;  off = i8; }
  else if (i8 < X8 +   W8){ src = wq; off = i8 - X8; }
  else if (i8 < X8 + 2*W8){ src = wk; off = i8 - (X8 +   W8); }
  else if (i8 < X8 + 3*W8){ src = wv; off = i8 - (X8 + 2*W8); }
  else                    { src = wo; off = i8 - (X8 + 3*W8); }
  const float4* p = (const float4*)src;
  float4 a = p[(long)off*2], b = p[(long)off*2 + 1];
  bf16x8 o;
  o[0]=(short)f2bf(a.x); o[1]=(short)f2bf(a.y); o[2]=(short)f2bf(a.z); o[3]=(short)f2bf(a.w);
  o[4]=(short)f2bf(b.x); o[5]=(short)f2bf(b.y); o[6]=(short)f2bf(b.z); o[7]=(short)f2bf(b.w);
  *(bf16x8*)(dst + (long)i8*8) = o;
}

// ------ 8-phase-style GEMM: 256x128 tile, BK=64, 8 waves, TRIPLE buffer ------
// 4 phases per K-tile: {ds_read frags | stage 2 loads of tile t+2 -> barrier
// -> lgkmcnt(0) -> setprio+8 MFMA -> barrier}. vmcnt(6) only at phase 4.
// Triple buffer: tile t+2 stages into buf (t+2)%3 - never aliases t or t+1.
// MODE 0: QKV fused (N=6144, 768 blocks = 3 CU-rounds): Q scaled, K, V transp.
// MODE 1: O-proj (N=2048, 256 blocks = 1 round): f32 out.
template<int MODE>
__global__ __launch_bounds__(512, 2) void gemm8(
    const ushort* __restrict__ A, const ushort* __restrict__ Bt,
    ushort* __restrict__ Qo, ushort* __restrict__ Ko, ushort* __restrict__ Vt,
    float* __restrict__ Cf)
{
  __shared__ ushort lds[3 * 24576];          // 3 x 48 KB = 144 KB
  const int NBX = (MODE == 0) ? 6 : 2;       // n-tiles per XCD chunk
  const int t = threadIdx.x;
  const int bid = blockIdx.x;
  const int xcd = bid & 7, local = bid >> 3;
  const int bm = local / NBX;
  const int bn = xcd * NBX + (local - bm * NBX);
  const int lane = t & 63;
  const int w = t >> 6;
  const int wr = w >> 2;                     // 0..1: 128-row half
  const int wcn = w & 3;                     // 0..3: 32-col group
  const int lr = lane & 15, lg = lane >> 4;

  // staging maps: A = 4 chunks/thread, B = 2 chunks/thread (16B each)
  // LDS slot 'slot' of row holds global chunk slot^(row&7)  (T2 swizzle)
  int aoff[4], aldo[4], boff[2], bldo[2];
#pragma unroll
  for (int i = 0; i < 4; ++i) {
    int c = i*512 + t, row = c >> 3, slot = c & 7, gc = slot ^ (row & 7);
    aoff[i] = row*DD + gc*8; aldo[i] = c*8;
  }
#pragma unroll
  for (int i = 0; i < 2; ++i) {
    int c = i*512 + t, row = c >> 3, slot = c & 7, gc = slot ^ (row & 7);
    boff[i] = row*DD + gc*8; bldo[i] = 16384 + c*8;
  }
  const ushort* Ab = A  + (long)(bm*256) * DD;
  const ushort* Bb = Bt + (long)(bn*128) * DD;

#define STG_A01(KT, BUF) do { const ushort* a_ = Ab + (KT)*64;          \
    ushort* l_ = lds + (BUF)*24576;                                     \
    gld_lds16(a_ + aoff[0], l_ + aldo[0]);                              \
    gld_lds16(a_ + aoff[1], l_ + aldo[1]); } while (0)
#define STG_A23(KT, BUF) do { const ushort* a_ = Ab + (KT)*64;          \
    ushort* l_ = lds + (BUF)*24576;                                     \
    gld_lds16(a_ + aoff[2], l_ + aldo[2]);                              \
    gld_lds16(a_ + aoff[3], l_ + aldo[3]); } while (0)
#define STG_B(KT, BUF)   do { const ushort* b_ = Bb + (KT)*64;          \
    ushort* l_ = lds + (BUF)*24576;                                     \
    gld_lds16(b_ + boff[0], l_ + bldo[0]);                              \
    gld_lds16(b_ + boff[1], l_ + bldo[1]); } while (0)

  // frag addresses: A row = wr*128+m*16+lr; B row = wcn*32+n*16+lr;
  // byte = base + row*128 + ((ks*4+lg)^(row&7))*16   (B at +32768 bytes)
#define LDA(dst, m, ks) { int row = wr*128 + (m)*16 + lr;               \
    (dst) = *(const bf16x8*)(cb + row*128 + ((((ks)*4+lg)^(row&7))*16)); }
#define LDB(dst, n, ks) { int row = wcn*32 + (n)*16 + lr;               \
    (dst) = *(const bf16x8*)(cb + 32768 + row*128 + ((((ks)*4+lg)^(row&7))*16)); }
#define MFMA8(h, av, bv) do {                                           \
    __builtin_amdgcn_s_setprio(1);                                      \
    _Pragma("unroll") for (int m = 0; m < 4; ++m)                       \
      _Pragma("unroll") for (int n = 0; n < 2; ++n)                     \
        acc[(h)*4+m][n] = __builtin_amdgcn_mfma_f32_16x16x32_bf16(      \
            av[m], bv[n], acc[(h)*4+m][n], 0, 0, 0);                    \
    __builtin_amdgcn_s_setprio(0); } while (0)
#define SB  __builtin_amdgcn_sched_barrier(0)
#define BAR __builtin_amdgcn_s_barrier()
#define LGKM0 asm volatile("s_waitcnt lgkmcnt(0)" ::: "memory")

  f32x4 acc[8][2] = {};
  const int T = DD / 64;                     // 32 K-tiles

  // prologue: stage tiles 0,1 fully; wait tile0 (6 outstanding = tile1)
  STG_A01(0, 0); STG_A23(0, 0); STG_B(0, 0);
  STG_A01(1, 1); STG_A23(1, 1); STG_B(1, 1);
  asm volatile("s_waitcnt vmcnt(6)" ::: "memory");
  SB; BAR; SB;

  int bcur = 0, bs = 2;
  for (int kt = 0; kt < T; ++kt) {
    const char* cb = (const char*)lds + bcur * 49152;
    const bool st = (kt + 2 < T);
    bf16x8 a0[4], a1[4], b0[2], b1[2];
    // ---- phase 1: (h0, ks0) ----
    LDA(a0[0],0,0); LDA(a0[1],1,0); LDA(a0[2],2,0); LDA(a0[3],3,0);
    LDB(b0[0],0,0); LDB(b0[1],1,0);
    if (st) STG_A01(kt+2, bs);
    SB; BAR; LGKM0; SB;
    MFMA8(0, a0, b0);
    SB; BAR; SB;
    // ---- phase 2: (h1, ks0) ----
    LDA(a1[0],4,0); LDA(a1[1],5,0); LDA(a1[2],6,0); LDA(a1[3],7,0);
    if (st) STG_A23(kt+2, bs);
    SB; BAR; LGKM0; SB;
    MFMA8(1, a1, b0);
    SB; BAR; SB;
    // ---- phase 3: (h0, ks1) ----
    LDA(a0[0],0,1); LDA(a0[1],1,1); LDA(a0[2],2,1); LDA(a0[3],3,1);
    LDB(b1[0],0,1); LDB(b1[1],1,1);
    if (st) STG_B(kt+2, bs);
    SB; BAR; LGKM0; SB;
    MFMA8(0, a0, b1);
    SB; BAR; SB;
    // ---- phase 4: (h1, ks1) + counted vmcnt (tile kt+1 landed) ----
    LDA(a1[0],4,1); LDA(a1[1],5,1); LDA(a1[2],6,1); LDA(a1[3],7,1);
    if (st) { asm volatile("s_waitcnt vmcnt(6)" ::: "memory"); }
    else    { asm volatile("s_waitcnt vmcnt(0)" ::: "memory"); }
    SB; BAR; LGKM0; SB;
    MFMA8(1, a1, b1);
    SB; BAR; SB;
    bcur = (bcur == 2) ? 0 : bcur + 1;
    bs   = (bs   == 2) ? 0 : bs   + 1;
  }
#undef STG_A01
#undef STG_A23
#undef STG_B
#undef LDA
#undef LDB
#undef MFMA8
#undef SB
#undef BAR
#undef LGKM0

  // epilogue: C/D layout col=lane&15, row=(lane>>4)*4+j
  const int crb = bm*256 + wr*128 + lg*4;
  if (MODE == 0) {
    const int region = bn >> 4;              // 0=Q, 1=K, 2=V
    const int ccb = (bn & 15)*128 + wcn*32 + lr;
    if (region < 2) {
      const float scale = (region == 0) ? (0.08838834764831845f * 1.4426950408889634f) : 1.0f;
      ushort* C = (region == 0) ? Qo : Ko;
#pragma unroll
      for (int m = 0; m < 8; ++m)
#pragma unroll
        for (int n = 0; n < 2; ++n)
#pragma unroll
          for (int j = 0; j < 4; ++j)
            C[(long)(crb + m*16 + j) * DD + (ccb + n*16)] = f2bf(acc[m][n][j] * scale);
    } else {
      // V transposed: Vt[(b*NH+h)*HDIM + d][s]; 4 j-rows = 4 contiguous s
#pragma unroll
      for (int m = 0; m < 8; ++m) {
        int sg = crb + m*16;
        int b2 = sg >> 11, s2 = sg & 2047;
#pragma unroll
        for (int n = 0; n < 2; ++n) {
          int colv = ccb + n*16;
          int h2 = colv >> 7, d2 = colv & 127;
          u16x4 pk;
          pk[0] = f2bf(acc[m][n][0]); pk[1] = f2bf(acc[m][n][1]);
          pk[2] = f2bf(acc[m][n][2]); pk[3] = f2bf(acc[m][n][3]);
          *(u16x4*)(Vt + ((long)((b2*NH + h2)*HDIM + d2)) * SS + s2) = pk;
        }
      }
    }
  } else {
    const int ccb = bn*128 + wcn*32 + lr;
#pragma unroll
    for (int m = 0; m < 8; ++m)
#pragma unroll
      for (int n = 0; n < 2; ++n)
#pragma unroll
        for (int j = 0; j < 4; ++j)
          Cf[(long)(crb + m*16 + j) * DD + (ccb + n*16)] = acc[m][n][j];
  }
}

// ---------------- causal flash attention (8 waves x 16 q-rows) ---------------
// K staged via global_load_lds with pre-swizzled source (read XOR (r&7)<<4);
// V already transposed in global -> staged the same way; no scalar transpose.
__global__ __launch_bounds__(512, 4) void attn_fwd(
    const ushort* __restrict__ Qb, const ushort* __restrict__ Kb,
    const ushort* __restrict__ Vtg, ushort* __restrict__ Ob)
{
  __shared__ ushort Ks[64*128];     // [k][d] rows 256B, XOR-swizzled chunks
  __shared__ ushort Vs[128*64];     // [d][k] rows 128B, XOR-swizzled chunks
  __shared__ ushort Ps[8*16*72];    // per-wave P [16][64], padded stride 72

  const int bid = blockIdx.x;
  const int qt = 15 - (bid >> 5);   // LPT: heaviest q-tiles first
  const int bh = bid & 31;
  const int b = bh >> 4, h = bh & 15;
  const int t = threadIdx.x;
  const int lane = t & 63;
  const int wq = t >> 6;            // 0..7
  const int lr = lane & 15, lg = lane >> 4;

  const int qbase = qt * 128;
  const long rowQ = (long)(b * SS + qbase + wq * 16);

  bf16x8 qf[4];                     // Q rows of this wave, pre-scaled
#pragma unroll
  for (int c = 0; c < 4; ++c)
    qf[c] = *(const bf16x8*)(Qb + (rowQ + lr) * DD + h*HDIM + c*32 + lg*8);

  f32x4 accO[8] = {};
  float mrow[4], lrow[4];
#pragma unroll
  for (int j = 0; j < 4; ++j) { mrow[j] = -1e30f; lrow[j] = 0.f; }

  // K staging: 1024 16B-chunks; thread t owns chunks t and 512+t
  const ushort* Kgb = Kb + (long)(b * SS) * DD + h * HDIM;
  const int kr0 = t >> 4, kr1 = 32 + (t >> 4), kci = t & 15;
  const ushort* gk0 = Kgb + (long)kr0 * DD + (kci ^ (kr0 & 7)) * 8;
  const ushort* gk1 = Kgb + (long)kr1 * DD + (kci ^ (kr1 & 7)) * 8;
  ushort* lk0 = Ks + t*8;
  ushort* lk1 = Ks + 4096 + t*8;

  // V^T staging: rows d (128B), 8 chunks each
  const ushort* Vgb = Vtg + (long)(bh * HDIM) * SS;
  const int vd0 = t >> 3, vd1 = 64 + (t >> 3), vci = t & 7;
  const ushort* gv0 = Vgb + (long)vd0 * SS + (vci ^ (vd0 & 7)) * 8;
  const ushort* gv1 = Vgb + (long)vd1 * SS + (vci ^ (vd1 & 7)) * 8;
  ushort* lv0 = Vs + t*8;
  ushort* lv1 = Vs + 4096 + t*8;

  const int ktmax = 2*qt + 1;
  const int qminw = qbase + wq*16;        // wave's FIRST q-row (mask trigger)
  const int qmaxw = qminw + 15;           // wave's last q-row (skip test)
  ushort* myP = Ps + wq * (16*72);

  for (int kt = 0; kt <= ktmax; ++kt) {
    const int k0 = kt * 64;
    gld_lds16(gk0, lk0); gld_lds16(gk1, lk1);
    gld_lds16(gv0, lv0); gld_lds16(gv1, lv1);
    gk0 += (long)64 * DD; gk1 += (long)64 * DD;
    gv0 += 64; gv1 += 64;
    __syncthreads();                 // drains vmcnt -> LDS tiles ready

    if (k0 <= qmaxw) {
      f32x4 sc[4] = {};
#pragma unroll
      for (int n = 0; n < 4; ++n) {  // S = Q K^T (this wave's 16 q-rows)
        int r = n*16 + lr;
        int swz = (r & 7) << 4;
#pragma unroll
        for (int c = 0; c < 4; ++c) {
          bf16x8 kf = *(const bf16x8*)((const char*)Ks + ((r*256 + c*64 + lg*16) ^ swz));
          sc[n] = __builtin_amdgcn_mfma_f32_16x16x32_bf16(qf[c], kf, sc[n], 0,0,0);
        }
      }
      if (k0 + 63 > qminw) {         // tile has keys beyond wave's FIRST row
#pragma unroll
        for (int n = 0; n < 4; ++n)
#pragma unroll
          for (int j = 0; j < 4; ++j) {
            int kpos = k0 + n*16 + lr;
            int qpos = qminw + lg*4 + j;
            if (kpos > qpos) sc[n][j] = -1e30f;
          }
      }
      float al[4];
#pragma unroll
      for (int j = 0; j < 4; ++j) {  // online softmax in log2 domain
        float tm = fmaxf(fmaxf(sc[0][j], sc[1][j]), fmaxf(sc[2][j], sc[3][j]));
#pragma unroll
        for (int off = 1; off < 16; off <<= 1) tm = fmaxf(tm, __shfl_xor(tm, off));
        float mn = fmaxf(mrow[j], tm);
        float a = fast_exp2(mrow[j] - mn);
        mrow[j] = mn;
        float ts = 0.f;
#pragma unroll
        for (int n = 0; n < 4; ++n) {
          float p = fast_exp2(sc[n][j] - mn);
          sc[n][j] = p; ts += p;
        }
#pragma unroll
        for (int off = 1; off < 16; off <<= 1) ts += __shfl_xor(ts, off);
        lrow[j] = lrow[j] * a + ts;
        al[j] = a;
      }
#pragma unroll
      for (int dg = 0; dg < 8; ++dg) {
        f32x4 v = accO[dg];
        v[0] *= al[0]; v[1] *= al[1]; v[2] *= al[2]; v[3] *= al[3];
        accO[dg] = v;
      }
#pragma unroll
      for (int n = 0; n < 4; ++n)    // P -> per-wave LDS (D-layout -> A-layout)
#pragma unroll
        for (int j = 0; j < 4; ++j)
          myP[(lg*4 + j)*72 + n*16 + lr] = f2bf(sc[n][j]);
      bf16x8 pa0 = *(const bf16x8*)(myP + lr*72 + lg*8);
      bf16x8 pa1 = *(const bf16x8*)(myP + lr*72 + 32 + lg*8);
#pragma unroll
      for (int dg = 0; dg < 8; ++dg) {   // O += P V
        int d = dg*16 + lr;
        int vswz = (d & 7) << 4;
        bf16x8 v0 = *(const bf16x8*)((const char*)Vs + ((d*128 + lg*16) ^ vswz));
        bf16x8 v1 = *(const bf16x8*)((const char*)Vs + ((d*128 + 64 + lg*16) ^ vswz));
        accO[dg] = __builtin_amdgcn_mfma_f32_16x16x32_bf16(pa0, v0, accO[dg], 0,0,0);
        accO[dg] = __builtin_amdgcn_mfma_f32_16x16x32_bf16(pa1, v1, accO[dg], 0,0,0);
      }
    }
    __syncthreads();                 // reads done before restage
  }

  float inv[4];
#pragma unroll
  for (int j = 0; j < 4; ++j) inv[j] = 1.0f / lrow[j];
  ushort* Og = Ob + rowQ * DD + h * HDIM;
#pragma unroll
  for (int dg = 0; dg < 8; ++dg)
#pragma unroll
    for (int j = 0; j < 4; ++j)
      Og[(long)(lg*4 + j) * DD + dg*16 + lr] = f2bf(accO[dg][j] * inv[j]);
}

// ---------------- launch ----------------------------------------------------
extern "C" void kernel_launch(void* const* d_in, const int* in_sizes, int n_in,
                              void* d_out, int out_size, void* d_ws, size_t ws_size,
                              hipStream_t stream) {
  const float* x  = (const float*)d_in[0];
  const float* Wq = (const float*)d_in[1];
  const float* Wk = (const float*)d_in[2];
  const float* Wv = (const float*)d_in[3];
  const float* Wo = (const float*)d_in[4];

  ushort* ws  = (ushort*)d_ws;
  ushort* xb  = ws;                         // x bf16; later reused as attn-out
  ushort* wqb = ws  + (long)MM*DD;          // wq/wk/wv contiguous = fused Bt
  ushort* wkb = wqb + (long)DD*DD;
  ushort* wvb = wkb + (long)DD*DD;
  ushort* wob = wvb + (long)DD*DD;
  ushort* Qb  = wob + (long)DD*DD;
  ushort* Kb  = Qb  + (long)MM*DD;
  ushort* Vtg = Kb  + (long)MM*DD;          // V stored transposed [bh*128+d][s]
  (void)wkb; (void)wvb;

  const int CVT_BLOCKS = (MM*DD + 4*DD*DD) / 8 / 256;   // 12288
  cvt_all<<<CVT_BLOCKS, 256, 0, stream>>>(x, Wq, Wk, Wv, Wo, ws);

  gemm8<0><<<768, 512, 0, stream>>>(xb, wqb, Qb, Kb, Vtg, nullptr);

  attn_fwd<<<512, 512, 0, stream>>>(Qb, Kb, Vtg, xb);   // attn out -> xb

  gemm8<1><<<256, 512, 0, stream>>>(xb, wob, nullptr, nullptr, nullptr,
                                    (float*)d_out);
}